// Round 3
// baseline (460.069 us; speedup 1.0000x reference)
//
#include <hip/hip_runtime.h>

#define NQv 20000
#define NSv 8192
#define Cv  112
#define CLSv 20
#define INFF 3.4e38f

#define P_BLOCKS 32
#define P_THREADS 256
#define P_NW (P_BLOCKS * P_THREADS / 64)   // 128 waves

#define M_THREADS 256
#define M_WPB 4
#define QPB 32                              // 8 queries/wave * 4 waves
#define M_BLOCKS ((NQv + QPB - 1) / QPB)    // 625
#define CHUNK 2048
#define NCH (NSv / CHUNK)                   // 4

#define WS_PART 16                          // float offset of pool partials in ws

__device__ __forceinline__ float bf2f(unsigned short u) {
    union { unsigned int i; float f; } v; v.i = ((unsigned int)u) << 16; return v.f;
}
__device__ __forceinline__ unsigned short f2bf(float f) {
    union { float f; unsigned int i; } v; v.f = f;
    unsigned int r = v.i + 0x7fffu + ((v.i >> 16) & 1u);
    return (unsigned short)(r >> 16);
}
template<bool F32>
__device__ __forceinline__ float ld1(const void* b, int i) {
    if (F32) return ((const float*)b)[i];
    return bf2f(((const unsigned short*)b)[i]);
}
template<bool F32>
__device__ __forceinline__ float2 ld2(const void* b, int i) {   // i even
    if (F32) return ((const float2*)b)[i >> 1];
    unsigned int u = ((const unsigned int*)b)[i >> 1];
    union { unsigned int x; float f; } a, c;
    a.x = u << 16; c.x = u & 0xffff0000u;
    return make_float2(a.f, c.f);
}

// dtype detector: gamma is all-ones. bf16 ones -> u16 (0x3F80,0x3F80); f32 1.0 -> (0x0000,0x3F80).
__global__ void k_detect(const unsigned short* __restrict__ g, int* __restrict__ flag) {
    if (threadIdx.x == 0) flag[0] = (g[0] == 0x3F80u && g[1] == 0x3F80u) ? 0 : 1;
}

// pooling partials: ws[WS_PART + b*113 + c], ws[WS_PART + b*113 + 112] = sum p
template<bool F32>
__global__ __launch_bounds__(P_THREADS) void k_pool(const void* __restrict__ fs7,
                                                    const void* __restrict__ wat,
                                                    float* __restrict__ ws,
                                                    const int* __restrict__ flag) {
    if (flag[0] != (F32 ? 1 : 0)) return;
    __shared__ float red[P_THREADS / 64][Cv + 1];
    int tid  = blockIdx.x * P_THREADS + threadIdx.x;
    int wid  = tid >> 6;
    int lw   = threadIdx.x >> 6;
    int lane = tid & 63;
    int l2   = lane * 2;
    float2 wa = make_float2(0.f, 0.f);
    if (lane < 56) wa = ld2<F32>(wat, l2);
    float gx = 0.f, gy = 0.f, z = 0.f;
    for (int i = wid; i < NSv; i += P_NW) {
        float2 f = make_float2(0.f, 0.f);
        if (lane < 56) f = ld2<F32>(fs7, i * Cv + l2);
        float part = f.x * wa.x + f.y * wa.y;
        #pragma unroll
        for (int off = 32; off; off >>= 1) part += __shfl_xor(part, off, 64);
        float p = __expf(part);              // |logit| < ~7, f32-safe without max-subtract
        gx = fmaf(p, f.x, gx);
        gy = fmaf(p, f.y, gy);
        z += p;
    }
    if (lane < 56) { red[lw][l2] = gx; red[lw][l2 + 1] = gy; }
    if (lane == 0) red[lw][Cv] = z;
    __syncthreads();
    int t = threadIdx.x;
    if (t < Cv + 1)
        ws[WS_PART + blockIdx.x * (Cv + 1) + t] = red[0][t] + red[1][t] + red[2][t] + red[3][t];
}

template<bool F32>
__global__ __launch_bounds__(M_THREADS) void k_main(
        const void* __restrict__ cq, const void* __restrict__ cs,
        const void* __restrict__ x7, const void* __restrict__ fs,
        const void* __restrict__ W1, const void* __restrict__ gma,
        const void* __restrict__ bta, const void* __restrict__ W2,
        const void* __restrict__ Wc, const void* __restrict__ bc,
        const float* __restrict__ part, const int* __restrict__ flag,
        void* __restrict__ outp) {
    if (flag[0] != (F32 ? 1 : 0)) return;

    __shared__ float4 s_pts[CHUNK];          // 32 KB: (-2x,-2y,-2z,|s|^2)
    __shared__ float  s_gate[Cv];
    __shared__ int    s_qi[QPB][3];
    __shared__ float  s_qw[QPB][3];
    __shared__ float  s_v[M_WPB][2 * Cv];
    __shared__ float  s_t[M_WPB][Cv];

    int tid = threadIdx.x;
    int widx = tid >> 6, lane = tid & 63;
    int qid = lane >> 3, sub = lane & 7;
    int q0 = blockIdx.x * QPB;
    int l2 = lane * 2;

    if (tid < Cv) {                          // gate = sigmoid(pooled mean)
        float st = 0.f, zt = 0.f;
        for (int b = 0; b < P_BLOCKS; ++b) {
            st += part[b * (Cv + 1) + tid];
            zt += part[b * (Cv + 1) + Cv];
        }
        s_gate[tid] = 1.0f / (1.0f + __expf(-(st / zt)));
    }

    int q = q0 + widx * 8 + qid;
    bool qv = q < NQv;
    float qx = 0.f, qy = 0.f, qz = 0.f;
    if (qv) { qx = ld1<F32>(cq, 3 * q); qy = ld1<F32>(cq, 3 * q + 1); qz = ld1<F32>(cq, 3 * q + 2); }

    // per-lane top-3 over this lane's 1/8 slice; e = |s|^2 - 2 q.s  (q^2 cancels in softmax)
    float e0 = INFF, e1 = INFF, e2 = INFF;
    int   j0 = 0, j1 = 0, j2 = 0;
    for (int c = 0; c < NCH; ++c) {
        for (int t = tid; t < CHUNK; t += M_THREADS) {
            int p = c * CHUNK + t;
            float x = ld1<F32>(cs, 3 * p), y = ld1<F32>(cs, 3 * p + 1), z = ld1<F32>(cs, 3 * p + 2);
            s_pts[t] = make_float4(-2.f * x, -2.f * y, -2.f * z, x * x + y * y + z * z);
        }
        __syncthreads();
        #pragma unroll 4
        for (int k = 0; k < CHUNK / 8; ++k) {
            int t = sub + (k << 3);          // 8-way broadcast across query groups
            float4 P = s_pts[t];
            float e = fmaf(qx, P.x, fmaf(qy, P.y, fmaf(qz, P.z, P.w)));
            if (e < e2) {
                int p = c * CHUNK + t;
                if (e < e1) {
                    e2 = e1; j2 = j1;
                    if (e < e0) { e1 = e0; j1 = j0; e0 = e; j0 = p; }
                    else        { e1 = e; j1 = p; }
                } else { e2 = e; j2 = p; }
            }
        }
        __syncthreads();
    }

    // merge 8 sub-lanes per query: 3 rounds of (value, index) argmin over the 8-group
    {
        int sel = 0;
        float rb[3]; int rj[3];
        #pragma unroll
        for (int r = 0; r < 3; ++r) {
            float cv = (sel == 0) ? e0 : (sel == 1) ? e1 : (sel == 2) ? e2 : INFF;
            int   ci = (sel == 0) ? j0 : (sel == 1) ? j1 : (sel == 2) ? j2 : 0x7fffffff;
            float mv = cv; int mi = ci;
            #pragma unroll
            for (int off = 1; off <= 4; off <<= 1) {
                float ov = __shfl_xor(mv, off, 64);
                int   oi = __shfl_xor(mi, off, 64);
                if (ov < mv || (ov == mv && oi < mi)) { mv = ov; mi = oi; }
            }
            rb[r] = mv; rj[r] = mi;
            if (cv == mv && ci == mi) sel++;
        }
        if (sub == 0 && qv) {
            int qi = widx * 8 + qid;
            float w1v = __expf(rb[0] - rb[1]);
            float w2v = __expf(rb[0] - rb[2]);
            float iw  = 1.0f / (1.0f + w1v + w2v);
            s_qw[qi][0] = iw; s_qw[qi][1] = w1v * iw; s_qw[qi][2] = w2v * iw;
            #pragma unroll
            for (int r = 0; r < 3; ++r) {
                int v = rj[r];
                s_qi[qi][r] = v < 0 ? 0 : (v >= NSv ? NSv - 1 : v);
            }
        }
    }
    __syncthreads();

    // wave-per-query MLP, 8 rounds
    for (int r = 0; r < 8; ++r) {
        int qq = q0 + widx * 8 + r;
        bool act = qq < NQv;
        if (act && lane < 56) {
            int qi = widx * 8 + r;
            int i0 = s_qi[qi][0], i1 = s_qi[qi][1], i2 = s_qi[qi][2];
            float w0 = s_qw[qi][0], w1v = s_qw[qi][1], w2v = s_qw[qi][2];
            float2 fq = ld2<F32>(x7, qq * Cv + l2);
            float2 m0 = ld2<F32>(fs, i0 * Cv + l2);
            float2 m1 = ld2<F32>(fs, i1 * Cv + l2);
            float2 m2 = ld2<F32>(fs, i2 * Cv + l2);
            s_v[widx][l2]          = fq.x * s_gate[l2];
            s_v[widx][l2 + 1]      = fq.y * s_gate[l2 + 1];
            s_v[widx][Cv + l2]     = w0 * m0.x + w1v * m1.x + w2v * m2.x;
            s_v[widx][Cv + l2 + 1] = w0 * m0.y + w1v * m1.y + w2v * m2.y;
        }
        __syncthreads();
        if (act && lane < 56) {              // h1 = v @ W1 -> BN affine -> ReLU
            float ax = 0.f, ay = 0.f;
            #pragma unroll 8
            for (int i = 0; i < 2 * Cv; ++i) {
                float vv = s_v[widx][i];
                float2 w = ld2<F32>(W1, i * Cv + l2);
                ax = fmaf(vv, w.x, ax); ay = fmaf(vv, w.y, ay);
            }
            float2 gm = ld2<F32>(gma, l2), bt = ld2<F32>(bta, l2);
            ax = fmaf(ax, gm.x, bt.x); ay = fmaf(ay, gm.y, bt.y);
            s_t[widx][l2]     = ax > 0.f ? ax : 0.f;
            s_t[widx][l2 + 1] = ay > 0.f ? ay : 0.f;
        }
        __syncthreads();
        if (act && lane < 56) {              // h2 = t @ W2
            float ax = 0.f, ay = 0.f;
            #pragma unroll 8
            for (int i = 0; i < Cv; ++i) {
                float vv = s_t[widx][i];
                float2 w = ld2<F32>(W2, i * Cv + l2);
                ax = fmaf(vv, w.x, ax); ay = fmaf(vv, w.y, ay);
            }
            s_v[widx][l2] = ax; s_v[widx][l2 + 1] = ay;
        }
        __syncthreads();
        if (act && lane < CLSv) {            // out = h2 @ W_cls + b_cls
            float acc = ld1<F32>(bc, lane);
            #pragma unroll 8
            for (int i = 0; i < Cv; ++i)
                acc = fmaf(s_v[widx][i], ld1<F32>(Wc, i * CLSv + lane), acc);
            if (F32) ((float*)outp)[qq * CLSv + lane] = acc;
            else     ((unsigned short*)outp)[qq * CLSv + lane] = f2bf(acc);
        }
        __syncthreads();
    }
}

extern "C" void kernel_launch(void* const* d_in, const int* in_sizes, int n_in,
                              void* d_out, int out_size, void* d_ws, size_t ws_size,
                              hipStream_t stream) {
    const void* cq  = d_in[0];
    const void* cs  = d_in[1];
    const void* x7  = d_in[2];
    const void* fs7 = d_in[3];
    const void* fs  = d_in[4];
    const void* wat = d_in[5];
    const void* W1  = d_in[6];
    const void* gma = d_in[7];
    const void* bta = d_in[8];
    const void* W2  = d_in[9];
    const void* Wc  = d_in[10];
    const void* bc  = d_in[11];
    int*   flag = (int*)d_ws;
    float* wsf  = (float*)d_ws;

    k_detect<<<1, 64, 0, stream>>>((const unsigned short*)gma, flag);
    k_pool<false><<<P_BLOCKS, P_THREADS, 0, stream>>>(fs7, wat, wsf, flag);
    k_pool<true ><<<P_BLOCKS, P_THREADS, 0, stream>>>(fs7, wat, wsf, flag);
    k_main<false><<<M_BLOCKS, M_THREADS, 0, stream>>>(cq, cs, x7, fs, W1, gma, bta, W2, Wc, bc,
                                                      wsf + WS_PART, flag, d_out);
    k_main<true ><<<M_BLOCKS, M_THREADS, 0, stream>>>(cq, cs, x7, fs, W1, gma, bta, W2, Wc, bc,
                                                      wsf + WS_PART, flag, d_out);
}

// Round 4
// 256.957 us; speedup vs baseline: 1.7905x; 1.7905x over previous
//
#include <hip/hip_runtime.h>

#define NQv 20000
#define NSv 8192
#define Cv  112
#define CLSv 20
#define INFF 3.4e38f

#define PB 32
#define PT 256
#define PNW (PB * PT / 64)      // 128 waves

#define MT 256
#define QT 32                   // queries per block
#define MB (NQv / QT)           // 625 blocks (exact)
#define CH 1024                 // scan chunk points
#define NCHv (NSv / CH)         // 8
#define VP 36                   // padded tile leading dim (float)

// ---- pooling partials: ws[b*113 + c] = sum p_i*feat[i][c]; ws[b*113+112] = sum p_i
__global__ __launch_bounds__(PT) void k_pool(const float* __restrict__ fs7,
                                             const float* __restrict__ wat,
                                             float* __restrict__ ws) {
    __shared__ float red[PT / 64][Cv + 1];
    int tid = blockIdx.x * PT + threadIdx.x;
    int wid = tid >> 6, lw = threadIdx.x >> 6, lane = tid & 63, l2 = lane * 2;
    float2 wa = make_float2(0.f, 0.f);
    if (lane < 56) wa = *(const float2*)(wat + l2);
    float gx = 0.f, gy = 0.f, z = 0.f;
    for (int i = wid; i < NSv; i += PNW) {
        float2 f = make_float2(0.f, 0.f);
        if (lane < 56) f = *(const float2*)(fs7 + i * Cv + l2);
        float part = f.x * wa.x + f.y * wa.y;
        #pragma unroll
        for (int off = 32; off; off >>= 1) part += __shfl_xor(part, off, 64);
        float p = __expf(part);              // |logit| small, f32-safe
        gx = fmaf(p, f.x, gx); gy = fmaf(p, f.y, gy); z += p;
    }
    if (lane < 56) { red[lw][l2] = gx; red[lw][l2 + 1] = gy; }
    if (lane == 0) red[lw][Cv] = z;
    __syncthreads();
    int t = threadIdx.x;
    if (t < Cv + 1)
        ws[blockIdx.x * (Cv + 1) + t] = red[0][t] + red[1][t] + red[2][t] + red[3][t];
}

// ---- fused: scan (top-3) + gate + batched MLP GEMM for 32 queries/block
__global__ __launch_bounds__(MT) void k_fused(
        const float* __restrict__ cq, const float* __restrict__ cs,
        const float* __restrict__ x7, const float* __restrict__ fs,
        const float* __restrict__ W1, const float* __restrict__ gma,
        const float* __restrict__ bta, const float* __restrict__ W2,
        const float* __restrict__ Wc, const float* __restrict__ bc,
        const float* __restrict__ part, float* __restrict__ out) {
    __shared__ float big[224 * VP];          // scan pts (aliased) -> V^T -> h2^T
    __shared__ float tT[Cv * VP];            // h1 post-BN-ReLU, transposed
    __shared__ float gate[Cv];
    __shared__ int   qi[QT][3];
    __shared__ float qw[QT][3];
    float4* pts = (float4*)big;              // 1024 * 16B = 16 KB <= 32.25 KB

    int tid = threadIdx.x;
    int q0 = blockIdx.x * QT;

    if (tid < Cv) {                          // gate = sigmoid(pooled mean)
        float st = 0.f, zt = 0.f;
        for (int b = 0; b < PB; ++b) {
            st += part[b * (Cv + 1) + tid];
            zt += part[b * (Cv + 1) + Cv];
        }
        gate[tid] = 1.0f / (1.0f + __expf(-(st / zt)));
    }

    int lane = tid & 63, widx = tid >> 6;
    int qid = lane >> 3, sub = lane & 7;
    int q = q0 + widx * 8 + qid;             // exact: 625*32 == 20000
    float qx = cq[3 * q], qy = cq[3 * q + 1], qz = cq[3 * q + 2];

    // scan: e = |s|^2 - 2 q.s  (q^2 cancels in softmax); per-lane top-3 over 1/8 slice
    float e0 = INFF, e1 = INFF, e2 = INFF;
    int   j0 = 0, j1 = 0, j2 = 0;
    for (int c = 0; c < NCHv; ++c) {
        __syncthreads();                     // protect pts from previous chunk's readers
        for (int t = tid; t < CH; t += MT) {
            int p = c * CH + t;
            float x = cs[3 * p], y = cs[3 * p + 1], z = cs[3 * p + 2];
            pts[t] = make_float4(-2.f * x, -2.f * y, -2.f * z, x * x + y * y + z * z);
        }
        __syncthreads();
        #pragma unroll 4
        for (int k = 0; k < CH / 8; ++k) {
            int t = sub + (k << 3);
            float4 P = pts[t];
            float e = fmaf(qx, P.x, fmaf(qy, P.y, fmaf(qz, P.z, P.w)));
            if (e < e2) {
                int p = c * CH + t;
                if (e < e1) {
                    e2 = e1; j2 = j1;
                    if (e < e0) { e1 = e0; j1 = j0; e0 = e; j0 = p; }
                    else        { e1 = e; j1 = p; }
                } else { e2 = e; j2 = p; }
            }
        }
    }
    // merge 8 sub-lanes: 3 rounds of (value,index) argmin over the 8-group
    {
        int sel = 0;
        float rb[3]; int rj[3];
        #pragma unroll
        for (int r = 0; r < 3; ++r) {
            float cv = (sel == 0) ? e0 : (sel == 1) ? e1 : (sel == 2) ? e2 : INFF;
            int   ci = (sel == 0) ? j0 : (sel == 1) ? j1 : (sel == 2) ? j2 : 0x7fffffff;
            float mv = cv; int mi = ci;
            #pragma unroll
            for (int off = 1; off <= 4; off <<= 1) {
                float ov = __shfl_xor(mv, off, 64);
                int   oi = __shfl_xor(mi, off, 64);
                if (ov < mv || (ov == mv && oi < mi)) { mv = ov; mi = oi; }
            }
            rb[r] = mv; rj[r] = mi;
            if (cv == mv && ci == mi) sel++;
        }
        if (sub == 0) {
            int qq = widx * 8 + qid;
            float w1v = __expf(rb[0] - rb[1]);
            float w2v = __expf(rb[0] - rb[2]);
            float iw  = 1.0f / (1.0f + w1v + w2v);
            qw[qq][0] = iw; qw[qq][1] = w1v * iw; qw[qq][2] = w2v * iw;
            #pragma unroll
            for (int r = 0; r < 3; ++r) {
                int v = rj[r];
                qi[qq][r] = v < 0 ? 0 : (v >= NSv ? NSv - 1 : v);
            }
        }
    }
    __syncthreads();

    // build V^T[224][VP]: rows 0..111 = gated x7, rows 112..223 = matched
    {
        int vq = tid >> 3, e8 = tid & 7;
        int gq = q0 + vq;
        int i0 = qi[vq][0], i1 = qi[vq][1], i2 = qi[vq][2];
        float w0 = qw[vq][0], w1v = qw[vq][1], w2v = qw[vq][2];
        #pragma unroll
        for (int r = 0; r < 14; ++r) {
            int k = e8 + (r << 3);
            big[k * VP + vq] = x7[gq * Cv + k] * gate[k];
            float m = w0 * fs[i0 * Cv + k] + w1v * fs[i1 * Cv + k] + w2v * fs[i2 * Cv + k];
            big[(Cv + k) * VP + vq] = m;
        }
    }
    __syncthreads();

    int tx = tid % 28, ty = tid / 28;        // 4 cols x 4 queries per thread, ty<8 active
    int cb = tx * 4, qb = ty * 4;

    // h1 = V @ W1 -> BN affine -> ReLU -> tT[c][q]
    if (ty < 8) {
        float acc[4][4] = {};
        #pragma unroll 4
        for (int k = 0; k < 2 * Cv; ++k) {
            float4 vv = *(const float4*)&big[k * VP + qb];
            float4 ww = *(const float4*)&W1[k * Cv + cb];
            #pragma unroll
            for (int i = 0; i < 4; ++i) {
                float v = (&vv.x)[i];
                acc[i][0] = fmaf(v, ww.x, acc[i][0]);
                acc[i][1] = fmaf(v, ww.y, acc[i][1]);
                acc[i][2] = fmaf(v, ww.z, acc[i][2]);
                acc[i][3] = fmaf(v, ww.w, acc[i][3]);
            }
        }
        #pragma unroll
        for (int j = 0; j < 4; ++j) {
            float g = gma[cb + j], b = bta[cb + j];
            #pragma unroll
            for (int i = 0; i < 4; ++i) {
                float h = fmaf(acc[i][j], g, b);
                tT[(cb + j) * VP + qb + i] = h > 0.f ? h : 0.f;
            }
        }
    }
    __syncthreads();

    // h2 = t @ W2 -> big[c][q] (V^T storage is dead now)
    if (ty < 8) {
        float acc[4][4] = {};
        #pragma unroll 4
        for (int k = 0; k < Cv; ++k) {
            float4 vv = *(const float4*)&tT[k * VP + qb];
            float4 ww = *(const float4*)&W2[k * Cv + cb];
            #pragma unroll
            for (int i = 0; i < 4; ++i) {
                float v = (&vv.x)[i];
                acc[i][0] = fmaf(v, ww.x, acc[i][0]);
                acc[i][1] = fmaf(v, ww.y, acc[i][1]);
                acc[i][2] = fmaf(v, ww.z, acc[i][2]);
                acc[i][3] = fmaf(v, ww.w, acc[i][3]);
            }
        }
        #pragma unroll
        for (int j = 0; j < 4; ++j)
            #pragma unroll
            for (int i = 0; i < 4; ++i)
                big[(cb + j) * VP + qb + i] = acc[i][j];
    }
    __syncthreads();

    // out = h2 @ Wc + bc : thread -> (q = tid&31, 3-col group cg = tid>>5)
    {
        int qq = tid & 31, cg = tid >> 5;
        int ob = cg * 3;
        if (ob < CLSv) {
            int nc = CLSv - ob; if (nc > 3) nc = 3;
            float a0 = bc[ob];
            float a1 = (nc > 1) ? bc[ob + 1] : 0.f;
            float a2 = (nc > 2) ? bc[ob + 2] : 0.f;
            #pragma unroll 4
            for (int k = 0; k < Cv; ++k) {
                float h = big[k * VP + qq];
                a0 = fmaf(h, Wc[k * CLSv + ob], a0);
                if (nc > 1) a1 = fmaf(h, Wc[k * CLSv + ob + 1], a1);
                if (nc > 2) a2 = fmaf(h, Wc[k * CLSv + ob + 2], a2);
            }
            float* o = out + (q0 + qq) * CLSv + ob;
            o[0] = a0;
            if (nc > 1) o[1] = a1;
            if (nc > 2) o[2] = a2;
        }
    }
}

extern "C" void kernel_launch(void* const* d_in, const int* in_sizes, int n_in,
                              void* d_out, int out_size, void* d_ws, size_t ws_size,
                              hipStream_t stream) {
    const float* cq  = (const float*)d_in[0];
    const float* cs  = (const float*)d_in[1];
    const float* x7  = (const float*)d_in[2];
    const float* fs7 = (const float*)d_in[3];
    const float* fs  = (const float*)d_in[4];
    const float* wat = (const float*)d_in[5];
    const float* W1  = (const float*)d_in[6];
    const float* gma = (const float*)d_in[7];
    const float* bta = (const float*)d_in[8];
    const float* W2  = (const float*)d_in[9];
    const float* Wc  = (const float*)d_in[10];
    const float* bc  = (const float*)d_in[11];
    float* ws  = (float*)d_ws;
    float* out = (float*)d_out;

    k_pool<<<PB, PT, 0, stream>>>(fs7, wat, ws);
    k_fused<<<MB, MT, 0, stream>>>(cq, cs, x7, fs, W1, gma, bta, W2, Wc, bc, ws, out);
}